// Round 6
// baseline (312.058 us; speedup 1.0000x reference)
//
#include <hip/hip_runtime.h>
#include <hip/hip_bf16.h>

#define H 1024
#define B 32
#define S 2048

typedef __attribute__((ext_vector_type(8))) _Float16 h8;
typedef __attribute__((ext_vector_type(4))) _Float16 h4;
typedef __attribute__((ext_vector_type(4))) float f32x4;

__device__ __forceinline__ float fast_tanh(float x) {
    float a = __builtin_fabsf(x);
    float e = __expf(2.0f * a);
    float r = 1.0f - 2.0f / (e + 1.0f);   // == tanh(a)
    return __builtin_copysignf(r, x);
}

__device__ __forceinline__ void gload_lds16(const void* g, void* l) {
    __builtin_amdgcn_global_load_lds(
        (const __attribute__((address_space(1))) unsigned int*)g,
        (__attribute__((address_space(3))) unsigned int*)l, 16, 0, 0);
}

__device__ __forceinline__ h8 cvt8(float4 a, float4 b) {
    return (h8){(_Float16)a.x, (_Float16)a.y, (_Float16)a.z, (_Float16)a.w,
                (_Float16)b.x, (_Float16)b.y, (_Float16)b.z, (_Float16)b.w};
}

// ---------------- proj_h = h @ Wh^T + b_attn  (32 x 1024) ----------------
__global__ __launch_bounds__(256) void proj_h_kernel(
    const float* __restrict__ hidden, const float* __restrict__ W,
    const float* __restrict__ b_attn, float* __restrict__ ph)
{
    const int b = blockIdx.y;
    const int tid = threadIdx.x;
    __shared__ float hs[H];
    const float4* hr = (const float4*)(hidden + (size_t)(B + b) * H); // hidden[-1]
    ((float4*)hs)[tid] = hr[tid];
    __syncthreads();
    const int w = tid >> 6, lane = tid & 63;
    const int o = blockIdx.x * 4 + w;
    const float* wr = W + (size_t)o * (2 * H);
    float acc = 0.f;
    #pragma unroll
    for (int i = 0; i < 16; ++i) {
        const int k = i * 64 + lane;
        acc += wr[k] * hs[k];
    }
    #pragma unroll
    for (int off = 32; off; off >>= 1) acc += __shfl_xor(acc, off);
    if (lane == 0) ph[b * H + o] = acc + b_attn[o];
}

// ---------------- We (f32) -> We_h (fp16), row-major [1024][1024] --------
__global__ __launch_bounds__(256) void conv_We(
    const float* __restrict__ W, _Float16* __restrict__ We_h)
{
    const int o = blockIdx.x;
    const int t = threadIdx.x;
    float4 f = *(const float4*)(W + (size_t)o * 2048 + 1024 + t * 4);
    h4 hv = {(_Float16)f.x, (_Float16)f.y, (_Float16)f.z, (_Float16)f.w};
    *(h4*)(We_h + (size_t)o * 1024 + t * 4) = hv;
}

// ------- score GEMM v7: 256x256 tile, BK=32, phase-pipelined ------------
// 1024 blocks (256 M x 4 N, XCD-chunked), 512 thr = 8 waves (2M x 4N).
// A: T14 reg-staged f32->fp16 (issue early, ds_write late). B: gload_lds.
// LDS: A[2][256][32]h @0 (2x16KB), B[2][256][32]h @32768, slds @65536 (4KB).
#define V7_LDS 69632
__global__ __launch_bounds__(512, 2) void score_v7(
    const float* __restrict__ enc, const _Float16* __restrict__ We_h,
    const float* __restrict__ ph, const float* __restrict__ v,
    float* __restrict__ partial)
{
    extern __shared__ __align__(16) char smem[];
    float* slds = (float*)(smem + 65536);

    const int tid = threadIdx.x;
    const int bid = blockIdx.x;
    const int xcd = bid & 7, idx = bid >> 3;
    const int lin = xcd * 128 + idx;       // contiguous chunk per XCD
    const int nt = lin & 3, mt = lin >> 2; // 4 N-blocks of one M-panel adjacent
    const int bb = mt >> 3;                // batch (8 M-tiles per batch)

    const int lane = tid & 63, wid = tid >> 6;
    const int wm = wid >> 2, wn = wid & 3;
    const int l15 = lane & 15, lg = lane >> 4;

    // A reg-stage map: row = tid>>1, f32 half = tid&1 (16 floats -> 2 LDS slots)
    const int ar = tid >> 1, ah = tid & 1;
    const int agA = (ar ^ (ar >> 2)) & 3;  // row swizzle
    // B DMA map: row = j*128 + (tid>>2), slot = tid&3
    const int br = tid >> 2, bs = tid & 3;
    const float*    Ag = enc + ((size_t)(mt * 256) + ar) * H + ah * 16;
    const _Float16* Bg = We_h + (size_t)(nt * 256) * H;

    f32x4 acc[8][4];
    #pragma unroll
    for (int mi = 0; mi < 8; ++mi)
        #pragma unroll
        for (int ni = 0; ni < 4; ++ni) acc[mi][ni] = (f32x4){0.f, 0.f, 0.f, 0.f};

    #define STAGE_B(buf, k0, j) { \
        const int n = (j) * 128 + br; \
        gload_lds16(Bg + (size_t)n * H + (k0) + ((bs ^ ((n ^ (n >> 2)) & 3)) * 8), \
                    smem + 32768 + (buf) * 16384 + n * 64 + bs * 16); }
    #define WRITE_A(buf, f) { \
        h8 w0 = cvt8(f[0], f[1]); h8 w1 = cvt8(f[2], f[3]); \
        char* dst = smem + (buf) * 16384 + ar * 64; \
        *(h8*)(dst + (((ah * 2)     ^ agA) * 16)) = w0; \
        *(h8*)(dst + (((ah * 2 + 1) ^ agA) * 16)) = w1; }

    // ---- prologue: stage tile 0 ----
    {
        float4 f[4];
        #pragma unroll
        for (int i = 0; i < 4; ++i) f[i] = *(const float4*)(Ag + i * 4);
        WRITE_A(0, f)
        STAGE_B(0, 0, 0)
        STAGE_B(0, 0, 1)
    }
    __syncthreads();

    #pragma unroll 2
    for (int t = 0; t < 32; ++t) {
        const int cur = t & 1, nxt = cur ^ 1;
        const char* Ac = smem + cur * 16384;
        const char* Bc = smem + 32768 + cur * 16384;
        const int k0n = (t + 1) * 32;

        // issue next tile's loads early (T14): A to regs, B direct to LDS
        float4 apre[4];
        if (t < 31) {
            const float* asrc = Ag + (size_t)k0n;
            #pragma unroll
            for (int i = 0; i < 4; ++i) apre[i] = *(const float4*)(asrc + i * 4);
            STAGE_B(nxt, k0n, 0)
            STAGE_B(nxt, k0n, 1)
        }
        __builtin_amdgcn_sched_barrier(0);

        // B fragments (shared across both M-half phases)
        h8 bfr[4];
        #pragma unroll
        for (int ni = 0; ni < 4; ++ni) {
            const int n = wn * 64 + ni * 16 + l15;
            bfr[ni] = *(const h8*)(Bc + n * 64 + ((lg ^ ((n ^ (n >> 2)) & 3)) * 16));
        }
        #pragma unroll
        for (int mh = 0; mh < 2; ++mh) {
            h8 af[4];
            #pragma unroll
            for (int fi = 0; fi < 4; ++fi) {
                const int r = wm * 128 + (mh * 4 + fi) * 16 + l15;
                af[fi] = *(const h8*)(Ac + r * 64 + ((lg ^ ((r ^ (r >> 2)) & 3)) * 16));
            }
            __builtin_amdgcn_s_setprio(1);
            #pragma unroll
            for (int fi = 0; fi < 4; ++fi)
                #pragma unroll
                for (int ni = 0; ni < 4; ++ni)
                    acc[mh * 4 + fi][ni] = __builtin_amdgcn_mfma_f32_16x16x32_f16(
                        af[fi], bfr[ni], acc[mh * 4 + fi][ni], 0, 0, 0);
            __builtin_amdgcn_s_setprio(0);
        }
        // write next A tile (loads have had ~2 phases to land)
        if (t < 31) WRITE_A(nxt, apre)
        __syncthreads();
    }
    #undef STAGE_B
    #undef WRITE_A

    // ---- epilogue: tanh + v-dot over this block's 256 cols -> row partials ----
    float vreg[4], preg[4];
    #pragma unroll
    for (int ni = 0; ni < 4; ++ni) {
        const int gcol = nt * 256 + wn * 64 + ni * 16 + l15;
        vreg[ni] = v[gcol];
        preg[ni] = ph[bb * H + gcol];
    }
    #pragma unroll
    for (int mi = 0; mi < 8; ++mi) {
        #pragma unroll
        for (int j = 0; j < 4; ++j) {
            float p = 0.f;
            #pragma unroll
            for (int ni = 0; ni < 4; ++ni)
                p += vreg[ni] * fast_tanh(acc[mi][ni][j] + preg[ni]);
            p += __shfl_xor(p, 1); p += __shfl_xor(p, 2);
            p += __shfl_xor(p, 4); p += __shfl_xor(p, 8);
            if (l15 == 0)
                slds[wn * 256 + wm * 128 + mi * 16 + lg * 4 + j] = p;
        }
    }
    __syncthreads();
    if (tid < 256)
        partial[(size_t)nt * (B * S) + mt * 256 + tid] =
            slds[tid] + slds[256 + tid] + slds[512 + tid] + slds[768 + tid];
}

// ---- fallback score (R4 path, B reg-staged from f32 W; only if ws tiny) ----
__global__ __launch_bounds__(256) void score_v4f(
    const float* __restrict__ enc, const float* __restrict__ Wf,
    const float* __restrict__ ph, const float* __restrict__ v,
    float* __restrict__ partial)
{
    __shared__ _Float16 As[128 * 64];
    __shared__ _Float16 Bs[128 * 64];
    __shared__ float slds[256];
    const int tid = threadIdx.x;
    const int bid = blockIdx.x;
    const int x  = bid & 7;
    const int ii = bid >> 3;
    const int nb = ii & 7;
    const int mt = (ii >> 3) * 8 + x;
    const int b  = mt >> 4;
    const int lane = tid & 63;
    const int wid  = tid >> 6;
    const int wm = wid >> 1, wn = wid & 1;
    const int l15 = lane & 15, lg = lane >> 4;
    const int arow  = tid >> 3;
    const int aslot = tid & 7;
    f32x4 acc[4][4];
    #pragma unroll
    for (int mi = 0; mi < 4; ++mi)
        #pragma unroll
        for (int ni = 0; ni < 4; ++ni) acc[mi][ni] = (f32x4){0.f, 0.f, 0.f, 0.f};
    for (int kt = 0; kt < 16; ++kt) {
        const int k0 = kt * 64;
        __syncthreads();
        #pragma unroll
        for (int p = 0; p < 4; ++p) {
            const int m = p * 32 + arow;
            const float* src = enc + (size_t)(mt * 128 + m) * H + k0 + aslot * 8;
            float4 f0 = *(const float4*)src;
            float4 f1 = *(const float4*)(src + 4);
            *(h8*)((char*)As + m * 128 + ((aslot ^ (m & 7)) * 16)) = cvt8(f0, f1);
        }
        #pragma unroll
        for (int p = 0; p < 4; ++p) {
            const int n  = p * 32 + arow;
            const int gn = nb * 128 + n;
            const float* src = Wf + (size_t)gn * 2048 + 1024 + k0 + aslot * 8;
            float4 f0 = *(const float4*)src;
            float4 f1 = *(const float4*)(src + 4);
            *(h8*)((char*)Bs + n * 128 + ((aslot ^ (n & 7)) * 16)) = cvt8(f0, f1);
        }
        __syncthreads();
        #pragma unroll
        for (int ks = 0; ks < 2; ++ks) {
            h8 ah[4], bh[4];
            const int sl = ks * 4 + lg;
            #pragma unroll
            for (int mi = 0; mi < 4; ++mi) {
                const int r = wm * 64 + mi * 16 + l15;
                ah[mi] = *(const h8*)((char*)As + r * 128 + 16 * (sl ^ (r & 7)));
            }
            #pragma unroll
            for (int ni = 0; ni < 4; ++ni) {
                const int r = wn * 64 + ni * 16 + l15;
                bh[ni] = *(const h8*)((char*)Bs + r * 128 + 16 * (sl ^ (r & 7)));
            }
            #pragma unroll
            for (int mi = 0; mi < 4; ++mi)
                #pragma unroll
                for (int ni = 0; ni < 4; ++ni)
                    acc[mi][ni] = __builtin_amdgcn_mfma_f32_16x16x32_f16(
                        ah[mi], bh[ni], acc[mi][ni], 0, 0, 0);
        }
    }
    float vreg[4], preg[4];
    #pragma unroll
    for (int ni = 0; ni < 4; ++ni) {
        const int gcol = nb * 128 + wn * 64 + ni * 16 + l15;
        vreg[ni] = v[gcol];
        preg[ni] = ph[b * H + gcol];
    }
    #pragma unroll
    for (int mi = 0; mi < 4; ++mi) {
        #pragma unroll
        for (int j = 0; j < 4; ++j) {
            float p = 0.f;
            #pragma unroll
            for (int ni = 0; ni < 4; ++ni)
                p += vreg[ni] * fast_tanh(acc[mi][ni][j] + preg[ni]);
            p += __shfl_xor(p, 1); p += __shfl_xor(p, 2);
            p += __shfl_xor(p, 4); p += __shfl_xor(p, 8);
            if (l15 == 0)
                slds[wn * 128 + wm * 64 + mi * 16 + lg * 4 + j] = p;
        }
    }
    __syncthreads();
    if (tid < 128)
        partial[(size_t)nb * (B * S) + mt * 128 + tid] = slds[tid] + slds[128 + tid];
}

// ---------------- softmax over S per batch (sums nparts N-partials) ------
__global__ __launch_bounds__(256) void softmax_kernel(
    const float* __restrict__ partial, float* __restrict__ attn, int nparts)
{
    const int b = blockIdx.x, tid = threadIdx.x;
    float xv[8];
    float m = -1e30f;
    #pragma unroll
    for (int i = 0; i < 8; ++i) {
        float s = 0.f;
        for (int nb = 0; nb < nparts; ++nb)
            s += partial[(size_t)nb * (B * S) + b * S + tid + i * 256];
        xv[i] = s;
        m = fmaxf(m, s);
    }
    #pragma unroll
    for (int off = 32; off; off >>= 1) m = fmaxf(m, __shfl_xor(m, off));
    __shared__ float wred[4], wsum[4];
    const int w = tid >> 6;
    if ((tid & 63) == 0) wred[w] = m;
    __syncthreads();
    const float M = fmaxf(fmaxf(wred[0], wred[1]), fmaxf(wred[2], wred[3]));
    float s = 0.f;
    #pragma unroll
    for (int i = 0; i < 8; ++i) { xv[i] = expf(xv[i] - M); s += xv[i]; }
    #pragma unroll
    for (int off = 32; off; off >>= 1) s += __shfl_xor(s, off);
    if ((tid & 63) == 0) wsum[w] = s;
    __syncthreads();
    const float inv = 1.f / (wsum[0] + wsum[1] + wsum[2] + wsum[3]);
    #pragma unroll
    for (int i = 0; i < 8; ++i) attn[b * S + tid + i * 256] = xv[i] * inv;
}

// ---------------- context: partial over S-chunks, then reduce ------------
__global__ __launch_bounds__(256) void ctx_partial(
    const float* __restrict__ enc, const float* __restrict__ attn,
    float* __restrict__ part, int rows)
{
    const int sc = blockIdx.x;
    const int b  = blockIdx.y;
    const int tid = threadIdx.x;
    const float* encb = enc + ((size_t)b * S + (size_t)sc * rows) * H;
    const float* wb = attn + b * S + sc * rows;
    __shared__ float wl[256];
    if (tid < rows) wl[tid] = wb[tid];
    __syncthreads();
    float4 acc = {0.f, 0.f, 0.f, 0.f};
    for (int s = 0; s < rows; ++s) {
        const float wgt = wl[s];
        const float4 e = *(const float4*)(encb + (size_t)s * H + tid * 4);
        acc.x += wgt * e.x; acc.y += wgt * e.y; acc.z += wgt * e.z; acc.w += wgt * e.w;
    }
    ((float4*)(part + ((size_t)(sc * B + b)) * H))[tid] = acc;
}

__global__ __launch_bounds__(256) void ctx_reduce(
    const float* __restrict__ part, float* __restrict__ ctx, int nch)
{
    const int i = blockIdx.x * 256 + threadIdx.x;
    float s = 0.f;
    for (int c = 0; c < nch; ++c) s += part[(size_t)c * (B * H) + i];
    ctx[i] = s;
}

extern "C" void kernel_launch(void* const* d_in, const int* in_sizes, int n_in,
                              void* d_out, int out_size, void* d_ws, size_t ws_size,
                              hipStream_t stream) {
    const float* hidden = (const float*)d_in[0];
    const float* enc    = (const float*)d_in[1];
    const float* W      = (const float*)d_in[2];
    const float* b_attn = (const float*)d_in[3];
    const float* v      = (const float*)d_in[4];
    float* ctx  = (float*)d_out;               // (B, H)
    float* attn = ctx + B * H;                 // (B, S)
    float* ws      = (float*)d_ws;
    float* region  = ws;                       // 524288 f32: score partials, then ctx part
    float* ph      = ws + 524288;              // 32768 f32
    _Float16* We_h = (_Float16*)(ws + 524288 + 32768);  // 1M halfs

    proj_h_kernel<<<dim3(H / 4, B), 256, 0, stream>>>(hidden, W, b_attn, ph);

    const size_t need_primary = (size_t)(524288 + 32768 + 524288) * 4;
    if (ws_size >= need_primary) {
        conv_We<<<1024, 256, 0, stream>>>(W, We_h);
        hipFuncSetAttribute((const void*)score_v7,
                            hipFuncAttributeMaxDynamicSharedMemorySize, V7_LDS);
        score_v7<<<1024, 512, V7_LDS, stream>>>(enc, We_h, ph, v, region);
        softmax_kernel<<<dim3(B), 256, 0, stream>>>(region, attn, 4);
    } else {
        score_v4f<<<4096, 256, 0, stream>>>(enc, W, ph, v, region);
        softmax_kernel<<<dim3(B), 256, 0, stream>>>(region, attn, 8);
    }
    ctx_partial<<<dim3(16, B), 256, 0, stream>>>(enc, attn, region, 128);
    ctx_reduce<<<dim3((B * H) / 256), 256, 0, stream>>>(region, ctx, 16);
}